// Round 1
// baseline (1535.081 us; speedup 1.0000x reference)
//
#include <hip/hip_runtime.h>
#include <hip/hip_bf16.h>

typedef __bf16 bf16x8 __attribute__((ext_vector_type(8)));
typedef float  floatx4 __attribute__((ext_vector_type(4)));

#define MFMA16(a, b, c) __builtin_amdgcn_mfma_f32_16x16x32_bf16((a), (b), (c), 0, 0, 0)

// Problem constants (B=4, S=4096, D=512, P=512)
static constexpr int BATCH = 4;
static constexpr int SEQ   = 4096;
static constexpr int DIM   = 512;   // == P == heads*key_dim
static constexpr int MTOT  = BATCH * SEQ;  // 16384

// ---------------------------------------------------------------------------
// Generic 64x64-tile MFMA GEMM:  Y[M x 512] = A[M x 512] * W[512 x 512] + bias
// A is fp32 or bf16 (converted to bf16 in staging); Y is bf16 or fp32.
// 256 threads = 4 waves; wave w owns rows [w*16, w*16+16) x all 64 cols.
// ---------------------------------------------------------------------------
template <typename AT, typename OT>
__global__ __launch_bounds__(256, 2) void gemm64(
    const AT* __restrict__ A, const float* __restrict__ W,
    const float* __restrict__ bias, OT* __restrict__ Y)
{
    // padded leading dim 72 (stride 144B: 16B-aligned rows, 2-way banks = free)
    __shared__ __bf16 As[64 * 72];
    __shared__ __bf16 BTs[64 * 72];   // BTs[n][k] = W[k][n]

    const int tid  = threadIdx.x;
    const int w    = tid >> 6;
    const int lane = tid & 63;
    const int quad = lane >> 4;
    const int l15  = lane & 15;
    const int m0   = blockIdx.x * 64;
    const int n0   = blockIdx.y * 64;

    floatx4 acc[4];
#pragma unroll
    for (int nt = 0; nt < 4; ++nt) acc[nt] = floatx4{0.f, 0.f, 0.f, 0.f};

    for (int k0 = 0; k0 < 512; k0 += 64) {
#pragma unroll
        for (int it = 0; it < 2; ++it) {
            const int flat = it * 2048 + tid * 8;
            const int r = flat >> 6;      // 0..63
            const int c = flat & 63;      // multiple of 8
            // --- A tile: As[r][c..c+8)
            bf16x8 av;
            if constexpr (sizeof(AT) == 4) {
                const float* ap = (const float*)A + (size_t)(m0 + r) * 512 + k0 + c;
#pragma unroll
                for (int j = 0; j < 8; ++j) av[j] = (__bf16)ap[j];
            } else {
                av = *reinterpret_cast<const bf16x8*>((const __bf16*)A + (size_t)(m0 + r) * 512 + k0 + c);
            }
            *reinterpret_cast<bf16x8*>(&As[r * 72 + c]) = av;
            // --- W tile (transposed into BTs): row r is k, cols c..c+8 are n
            const float* wp = W + (size_t)(k0 + r) * 512 + n0 + c;
#pragma unroll
            for (int j = 0; j < 8; ++j) BTs[(c + j) * 72 + r] = (__bf16)wp[j];
        }
        __syncthreads();

#pragma unroll
        for (int kk = 0; kk < 2; ++kk) {
            const bf16x8 af = *reinterpret_cast<const bf16x8*>(
                &As[(w * 16 + l15) * 72 + kk * 32 + quad * 8]);
#pragma unroll
            for (int nt = 0; nt < 4; ++nt) {
                const bf16x8 bfv = *reinterpret_cast<const bf16x8*>(
                    &BTs[(nt * 16 + l15) * 72 + kk * 32 + quad * 8]);
                acc[nt] = MFMA16(af, bfv, acc[nt]);
            }
        }
        __syncthreads();
    }

    // Epilogue: C/D layout row = quad*4 + reg, col = l15 (+16*nt)
#pragma unroll
    for (int nt = 0; nt < 4; ++nt) {
        const int col = n0 + nt * 16 + l15;
        const float bv = bias[col];
#pragma unroll
        for (int r = 0; r < 4; ++r) {
            const int row = m0 + w * 16 + quad * 4 + r;
            const float val = acc[nt][r] + bv;
            Y[(size_t)row * 512 + col] = (OT)val;
        }
    }
}

// ---------------------------------------------------------------------------
// Flash attention over full 512-dim "head". 1 block = (batch b, 64 q-rows).
// 4 waves x 16 rows. Q in registers; K tile row-major LDS; V tile transposed
// LDS; P round-trips LDS per-wave (C-layout -> A-layout). scale = 1/sqrt(64).
// ---------------------------------------------------------------------------
__global__ __launch_bounds__(256, 1) void flash_attn(
    const __bf16* __restrict__ q, const __bf16* __restrict__ k,
    const __bf16* __restrict__ v, __bf16* __restrict__ att)
{
    __shared__ __bf16 Kt[32 * 520];   // [key][p], padded stride 520
    __shared__ __bf16 Vt[512 * 40];   // [p][key], padded stride 40
    __shared__ __bf16 Pl[4 * 16 * 40];// per-wave P: [wave*16+row][key], stride 40

    const int tid  = threadIdx.x;
    const int w    = tid >> 6;
    const int lane = tid & 63;
    const int quad = lane >> 4;
    const int l15  = lane & 15;
    const int b    = blockIdx.y;
    const int q0   = blockIdx.x * 64;
    const size_t boff = (size_t)b * SEQ * 512;

    // Q fragments: 16 k-steps of 32, A-layout A[m=l15][k=quad*8+j]
    bf16x8 qf[16];
    {
        const __bf16* qrow = q + boff + (size_t)(q0 + w * 16 + l15) * 512;
#pragma unroll
        for (int kk = 0; kk < 16; ++kk)
            qf[kk] = *reinterpret_cast<const bf16x8*>(qrow + kk * 32 + quad * 8);
    }

    floatx4 o[32];
#pragma unroll
    for (int i = 0; i < 32; ++i) o[i] = floatx4{0.f, 0.f, 0.f, 0.f};
    float mrow[4], lrow[4];
#pragma unroll
    for (int r = 0; r < 4; ++r) { mrow[r] = -1e30f; lrow[r] = 0.f; }

    for (int t0 = 0; t0 < SEQ; t0 += 32) {
        // ---- stage K tile [32 x 512] and V^T tile [512 x 32]
#pragma unroll
        for (int it = 0; it < 8; ++it) {
            const int flat = it * 2048 + tid * 8;
            const int r = flat >> 9;      // 0..31 (key)
            const int c = flat & 511;     // multiple of 8 (p)
            const bf16x8 kv8 = *reinterpret_cast<const bf16x8*>(
                k + boff + (size_t)(t0 + r) * 512 + c);
            *reinterpret_cast<bf16x8*>(&Kt[r * 520 + c]) = kv8;
            const bf16x8 vv8 = *reinterpret_cast<const bf16x8*>(
                v + boff + (size_t)(t0 + r) * 512 + c);
#pragma unroll
            for (int j = 0; j < 8; ++j) Vt[(c + j) * 40 + r] = vv8[j];
        }
        __syncthreads();

        // ---- scores S[16 x 32] = Q . K^T  (k-dim = p = 512)
        floatx4 sa[2];
        sa[0] = floatx4{0.f, 0.f, 0.f, 0.f};
        sa[1] = floatx4{0.f, 0.f, 0.f, 0.f};
#pragma unroll
        for (int kk = 0; kk < 16; ++kk) {
#pragma unroll
            for (int nt = 0; nt < 2; ++nt) {
                const bf16x8 kf = *reinterpret_cast<const bf16x8*>(
                    &Kt[(nt * 16 + l15) * 520 + kk * 32 + quad * 8]);
                sa[nt] = MFMA16(qf[kk], kf, sa[nt]);
            }
        }

        // ---- online softmax (rows quad*4+r; cols spread over 16 lanes x 2 nt)
        float pv[2][4];
        float alpha[4];
#pragma unroll
        for (int r = 0; r < 4; ++r) {
            const float s0v = sa[0][r] * 0.125f;
            const float s1v = sa[1][r] * 0.125f;
            float tm = fmaxf(s0v, s1v);
#pragma unroll
            for (int off = 1; off < 16; off <<= 1) tm = fmaxf(tm, __shfl_xor(tm, off));
            const float mnew = fmaxf(mrow[r], tm);
            alpha[r] = __expf(mrow[r] - mnew);
            mrow[r] = mnew;
            const float p0 = __expf(s0v - mnew);
            const float p1 = __expf(s1v - mnew);
            pv[0][r] = p0; pv[1][r] = p1;
            float rs = p0 + p1;
#pragma unroll
            for (int off = 1; off < 16; off <<= 1) rs += __shfl_xor(rs, off);
            lrow[r] = lrow[r] * alpha[r] + rs;
        }

        // ---- P: C-layout -> LDS -> A-layout (per wave, no cross-wave sync)
#pragma unroll
        for (int nt = 0; nt < 2; ++nt)
#pragma unroll
            for (int r = 0; r < 4; ++r)
                Pl[(w * 16 + quad * 4 + r) * 40 + nt * 16 + l15] = (__bf16)pv[nt][r];

        // ---- rescale O by alpha (same row mapping as scores C-layout)
#pragma unroll
        for (int pt = 0; pt < 32; ++pt) {
#pragma unroll
            for (int r = 0; r < 4; ++r) o[pt][r] *= alpha[r];
        }

        // ---- PV: A = P[16 x 32] (one k-step), B = V[t][p] via Vt
        const bf16x8 pf = *reinterpret_cast<const bf16x8*>(
            &Pl[(w * 16 + l15) * 40 + quad * 8]);
#pragma unroll
        for (int pt = 0; pt < 32; ++pt) {
            const bf16x8 vf = *reinterpret_cast<const bf16x8*>(
                &Vt[(pt * 16 + l15) * 40 + quad * 8]);
            o[pt] = MFMA16(pf, vf, o[pt]);
        }
        __syncthreads();
    }

    // ---- epilogue: divide by l, write attended (bf16)
    __bf16* ab = att + boff;
#pragma unroll
    for (int pt = 0; pt < 32; ++pt) {
#pragma unroll
        for (int r = 0; r < 4; ++r) {
            const int row = q0 + w * 16 + quad * 4 + r;
            const float val = o[pt][r] / lrow[r];
            ab[(size_t)row * 512 + pt * 16 + l15] = (__bf16)val;
        }
    }
}

// ---------------------------------------------------------------------------
extern "C" void kernel_launch(void* const* d_in, const int* in_sizes, int n_in,
                              void* d_out, int out_size, void* d_ws, size_t ws_size,
                              hipStream_t stream)
{
    (void)in_sizes; (void)n_in; (void)out_size; (void)ws_size;

    const float* x  = (const float*)d_in[0];
    const float* Wq = (const float*)d_in[1];
    const float* bq = (const float*)d_in[2];
    const float* Wk = (const float*)d_in[3];
    const float* bk = (const float*)d_in[4];
    const float* Wv = (const float*)d_in[5];
    const float* bv = (const float*)d_in[6];
    const float* Wo = (const float*)d_in[7];
    const float* bo = (const float*)d_in[8];
    float* out = (float*)d_out;

    // workspace: q, k, v, attended as bf16 [16384 x 512] each (64 MB total)
    __bf16* qb = (__bf16*)d_ws;
    __bf16* kb = qb + (size_t)MTOT * 512;
    __bf16* vb = kb + (size_t)MTOT * 512;
    __bf16* ab = vb + (size_t)MTOT * 512;

    const dim3 gg(MTOT / 64, 512 / 64);  // 256 x 8
    gemm64<float, __bf16><<<gg, 256, 0, stream>>>(x, Wq, bq, qb);
    gemm64<float, __bf16><<<gg, 256, 0, stream>>>(x, Wk, bk, kb);
    gemm64<float, __bf16><<<gg, 256, 0, stream>>>(x, Wv, bv, vb);

    flash_attn<<<dim3(SEQ / 64, BATCH), 256, 0, stream>>>(qb, kb, vb, ab);

    gemm64<__bf16, float><<<gg, 256, 0, stream>>>(ab, Wo, bo, out);
}

// Round 2
// 922.269 us; speedup vs baseline: 1.6645x; 1.6645x over previous
//
#include <hip/hip_runtime.h>
#include <hip/hip_bf16.h>

typedef __bf16 bf16x8 __attribute__((ext_vector_type(8)));
typedef float  floatx4 __attribute__((ext_vector_type(4)));

#define MFMA16(a, b, c) __builtin_amdgcn_mfma_f32_16x16x32_bf16((a), (b), (c), 0, 0, 0)

// Problem constants (B=4, S=4096, D=512, P=512)
static constexpr int BATCH = 4;
static constexpr int SEQ   = 4096;
static constexpr int MTOT  = BATCH * SEQ;  // 16384

// ---------------------------------------------------------------------------
// 64x64-tile MFMA GEMM:  Y[M x 512] = A[M x 512] * W[512 x 512] + bias
// A fp32 or bf16 (converted to bf16 in staging); Y bf16 or fp32.
// TRANSOUT: write Y transposed per batch: Y[b][col][t] (t = row within batch),
// via an LDS round-trip of the block's 64x64 C tile (coalesced global writes).
// 256 threads = 4 waves; wave w owns rows [w*16, w*16+16) x all 64 cols.
// ---------------------------------------------------------------------------
template <typename AT, typename OT, bool TRANSOUT>
__global__ __launch_bounds__(256, 2) void gemm64(
    const AT* __restrict__ A, const float* __restrict__ W,
    const float* __restrict__ bias, OT* __restrict__ Y)
{
    // padded leading dim 72 (stride 144B: 16B-aligned rows, 2-way banks = free)
    __shared__ __bf16 As[64 * 72];
    __shared__ __bf16 BTs[64 * 72];   // BTs[n][k] = W[k][n]
    __shared__ __bf16 Cs[TRANSOUT ? 64 * 80 : 1]; // [col][row], stride 80 (16B-aligned rows)

    const int tid  = threadIdx.x;
    const int w    = tid >> 6;
    const int lane = tid & 63;
    const int quad = lane >> 4;
    const int l15  = lane & 15;
    const int m0   = blockIdx.x * 64;
    const int n0   = blockIdx.y * 64;

    floatx4 acc[4];
#pragma unroll
    for (int nt = 0; nt < 4; ++nt) acc[nt] = floatx4{0.f, 0.f, 0.f, 0.f};

    for (int k0 = 0; k0 < 512; k0 += 64) {
#pragma unroll
        for (int it = 0; it < 2; ++it) {
            const int flat = it * 2048 + tid * 8;
            const int r = flat >> 6;      // 0..63
            const int c = flat & 63;      // multiple of 8
            // --- A tile: As[r][c..c+8)
            bf16x8 av;
            if constexpr (sizeof(AT) == 4) {
                const float* ap = (const float*)A + (size_t)(m0 + r) * 512 + k0 + c;
#pragma unroll
                for (int j = 0; j < 8; ++j) av[j] = (__bf16)ap[j];
            } else {
                av = *reinterpret_cast<const bf16x8*>((const __bf16*)A + (size_t)(m0 + r) * 512 + k0 + c);
            }
            *reinterpret_cast<bf16x8*>(&As[r * 72 + c]) = av;
            // --- W tile (transposed into BTs): row r is k, cols c..c+8 are n
            const float* wp = W + (size_t)(k0 + r) * 512 + n0 + c;
#pragma unroll
            for (int j = 0; j < 8; ++j) BTs[(c + j) * 72 + r] = (__bf16)wp[j];
        }
        __syncthreads();

#pragma unroll
        for (int kk = 0; kk < 2; ++kk) {
            const bf16x8 af = *reinterpret_cast<const bf16x8*>(
                &As[(w * 16 + l15) * 72 + kk * 32 + quad * 8]);
#pragma unroll
            for (int nt = 0; nt < 4; ++nt) {
                const bf16x8 bfv = *reinterpret_cast<const bf16x8*>(
                    &BTs[(nt * 16 + l15) * 72 + kk * 32 + quad * 8]);
                acc[nt] = MFMA16(af, bfv, acc[nt]);
            }
        }
        __syncthreads();
    }

    if constexpr (!TRANSOUT) {
        // C/D layout: row = quad*4 + reg, col = l15 (+16*nt)
#pragma unroll
        for (int nt = 0; nt < 4; ++nt) {
            const int col = n0 + nt * 16 + l15;
            const float bv = bias[col];
#pragma unroll
            for (int r = 0; r < 4; ++r) {
                const int row = m0 + w * 16 + quad * 4 + r;
                Y[(size_t)row * 512 + col] = (OT)(acc[nt][r] + bv);
            }
        }
    } else {
        // Stage C^T tile in LDS, then coalesced row writes of Y[b][col][t].
#pragma unroll
        for (int nt = 0; nt < 4; ++nt) {
            const int col = nt * 16 + l15;
            const float bv = bias[n0 + col];
#pragma unroll
            for (int r = 0; r < 4; ++r) {
                const int row = w * 16 + quad * 4 + r;
                Cs[col * 80 + row] = (__bf16)(acc[nt][r] + bv);
            }
        }
        __syncthreads();
        const int bb = m0 >> 12;        // batch
        const int tb = m0 & 4095;       // t base within batch
        __bf16* yb = (__bf16*)Y + (size_t)bb * 512 * 4096;
#pragma unroll
        for (int it = 0; it < 2; ++it) {
            const int flat = it * 2048 + tid * 8;
            const int pl = flat >> 6;     // local col 0..63
            const int c  = flat & 63;     // local row chunk, multiple of 8
            const bf16x8 vv = *reinterpret_cast<const bf16x8*>(&Cs[pl * 80 + c]);
            *reinterpret_cast<bf16x8*>(&yb[(size_t)(n0 + pl) * 4096 + tb + c]) = vv;
        }
    }
}

// ---------------------------------------------------------------------------
// Flash attention over full 512-dim "head". 1 block = (batch b, 64 q-rows).
// 4 waves x 16 rows. Q in registers; K tile [32 x 512] row-major LDS (pad 520);
// V tile [512 x 32] staged DENSE from pre-transposed vT (conflict-free);
// P round-trips LDS per-wave (C-layout -> A-layout). scale = 1/sqrt(64).
// ---------------------------------------------------------------------------
__global__ __launch_bounds__(256, 1) void flash_attn(
    const __bf16* __restrict__ q, const __bf16* __restrict__ k,
    const __bf16* __restrict__ vT, __bf16* __restrict__ att)
{
    __shared__ __bf16 Kt[32 * 520];    // [key][p], padded stride 520
    __shared__ __bf16 Vt[512 * 32];    // [p][key], dense
    __shared__ __bf16 Pl[4 * 16 * 40]; // per-wave P: [wave*16+row][key], stride 40

    const int tid  = threadIdx.x;
    const int w    = tid >> 6;
    const int lane = tid & 63;
    const int quad = lane >> 4;
    const int l15  = lane & 15;
    const int b    = blockIdx.y;
    const int q0   = blockIdx.x * 64;
    const size_t boff = (size_t)b * SEQ * 512;

    // Q fragments: 16 k-steps of 32, A-layout A[m=l15][k=quad*8+j]
    bf16x8 qf[16];
    {
        const __bf16* qrow = q + boff + (size_t)(q0 + w * 16 + l15) * 512;
#pragma unroll
        for (int kk = 0; kk < 16; ++kk)
            qf[kk] = *reinterpret_cast<const bf16x8*>(qrow + kk * 32 + quad * 8);
    }

    floatx4 o[32];
#pragma unroll
    for (int i = 0; i < 32; ++i) o[i] = floatx4{0.f, 0.f, 0.f, 0.f};
    float mrow[4], lrow[4];
#pragma unroll
    for (int r = 0; r < 4; ++r) { mrow[r] = -1e30f; lrow[r] = 0.f; }

    const __bf16* vTb = vT + boff;  // [p][t] rows of length 4096

    for (int t0 = 0; t0 < SEQ; t0 += 32) {
        // ---- stage K tile [32 x 512] (row-major) and V tile [512 x 32] (dense)
#pragma unroll
        for (int it = 0; it < 8; ++it) {
            const int flat = it * 2048 + tid * 8;
            {   // K: row r = key, cols c..c+8 = p
                const int r = flat >> 9;
                const int c = flat & 511;
                const bf16x8 kv8 = *reinterpret_cast<const bf16x8*>(
                    k + boff + (size_t)(t0 + r) * 512 + c);
                *reinterpret_cast<bf16x8*>(&Kt[r * 520 + c]) = kv8;
            }
            {   // V: row p, 8 keys starting at tc (dense b128 writes, 0-conflict)
                const int p  = flat >> 5;
                const int tc = flat & 31;
                const bf16x8 vv8 = *reinterpret_cast<const bf16x8*>(
                    vTb + (size_t)p * 4096 + t0 + tc);
                *reinterpret_cast<bf16x8*>(&Vt[p * 32 + tc]) = vv8;
            }
        }
        __syncthreads();

        // ---- scores S[16 x 32] = Q . K^T  (k-dim = p = 512)
        floatx4 sa[2];
        sa[0] = floatx4{0.f, 0.f, 0.f, 0.f};
        sa[1] = floatx4{0.f, 0.f, 0.f, 0.f};
#pragma unroll
        for (int kk = 0; kk < 16; ++kk) {
#pragma unroll
            for (int nt = 0; nt < 2; ++nt) {
                const bf16x8 kf = *reinterpret_cast<const bf16x8*>(
                    &Kt[(nt * 16 + l15) * 520 + kk * 32 + quad * 8]);
                sa[nt] = MFMA16(qf[kk], kf, sa[nt]);
            }
        }

        // ---- online softmax (rows quad*4+r; cols spread over 16 lanes x 2 nt)
        float pv[2][4];
        float alpha[4];
#pragma unroll
        for (int r = 0; r < 4; ++r) {
            const float s0v = sa[0][r] * 0.125f;
            const float s1v = sa[1][r] * 0.125f;
            float tm = fmaxf(s0v, s1v);
#pragma unroll
            for (int off = 1; off < 16; off <<= 1) tm = fmaxf(tm, __shfl_xor(tm, off));
            const float mnew = fmaxf(mrow[r], tm);
            alpha[r] = __expf(mrow[r] - mnew);
            mrow[r] = mnew;
            const float p0 = __expf(s0v - mnew);
            const float p1 = __expf(s1v - mnew);
            pv[0][r] = p0; pv[1][r] = p1;
            float rs = p0 + p1;
#pragma unroll
            for (int off = 1; off < 16; off <<= 1) rs += __shfl_xor(rs, off);
            lrow[r] = lrow[r] * alpha[r] + rs;
        }

        // ---- P: C-layout -> LDS -> A-layout (per wave, no cross-wave sync)
#pragma unroll
        for (int nt = 0; nt < 2; ++nt)
#pragma unroll
            for (int r = 0; r < 4; ++r)
                Pl[(w * 16 + quad * 4 + r) * 40 + nt * 16 + l15] = (__bf16)pv[nt][r];

        // ---- rescale O by alpha (same row mapping as scores C-layout)
#pragma unroll
        for (int pt = 0; pt < 32; ++pt) {
#pragma unroll
            for (int r = 0; r < 4; ++r) o[pt][r] *= alpha[r];
        }

        // ---- PV: A = P[16 x 32] (one k-step), B = V[t][p] via Vt (dense read)
        const bf16x8 pf = *reinterpret_cast<const bf16x8*>(
            &Pl[(w * 16 + l15) * 40 + quad * 8]);
#pragma unroll
        for (int pt = 0; pt < 32; ++pt) {
            const bf16x8 vf = *reinterpret_cast<const bf16x8*>(
                &Vt[(pt * 16 + l15) * 32 + quad * 8]);
            o[pt] = MFMA16(pf, vf, o[pt]);
        }
        __syncthreads();
    }

    // ---- epilogue: divide by l, write attended (bf16)
    __bf16* ab = att + boff;
#pragma unroll
    for (int pt = 0; pt < 32; ++pt) {
#pragma unroll
        for (int r = 0; r < 4; ++r) {
            const int row = q0 + w * 16 + quad * 4 + r;
            const float val = o[pt][r] / lrow[r];
            ab[(size_t)row * 512 + pt * 16 + l15] = (__bf16)val;
        }
    }
}

// ---------------------------------------------------------------------------
extern "C" void kernel_launch(void* const* d_in, const int* in_sizes, int n_in,
                              void* d_out, int out_size, void* d_ws, size_t ws_size,
                              hipStream_t stream)
{
    (void)in_sizes; (void)n_in; (void)out_size; (void)ws_size;

    const float* x  = (const float*)d_in[0];
    const float* Wq = (const float*)d_in[1];
    const float* bq = (const float*)d_in[2];
    const float* Wk = (const float*)d_in[3];
    const float* bk = (const float*)d_in[4];
    const float* Wv = (const float*)d_in[5];
    const float* bv = (const float*)d_in[6];
    const float* Wo = (const float*)d_in[7];
    const float* bo = (const float*)d_in[8];
    float* out = (float*)d_out;

    // workspace: q, k (row-major), vT (per-batch transposed [b][p][t]),
    // attended -- bf16 [16384 x 512] each (64 MB total)
    __bf16* qb  = (__bf16*)d_ws;
    __bf16* kb  = qb  + (size_t)MTOT * 512;
    __bf16* vbT = kb  + (size_t)MTOT * 512;
    __bf16* ab  = vbT + (size_t)MTOT * 512;

    const dim3 gg(MTOT / 64, 512 / 64);  // 256 x 8
    gemm64<float, __bf16, false><<<gg, 256, 0, stream>>>(x, Wq, bq, qb);
    gemm64<float, __bf16, false><<<gg, 256, 0, stream>>>(x, Wk, bk, kb);
    gemm64<float, __bf16, true ><<<gg, 256, 0, stream>>>(x, Wv, bv, vbT);

    flash_attn<<<dim3(SEQ / 64, BATCH), 256, 0, stream>>>(qb, kb, vbT, ab);

    gemm64<__bf16, float, false><<<gg, 256, 0, stream>>>(ab, Wo, bo, out);
}